// Round 4
// baseline (132.877 us; speedup 1.0000x reference)
//
#include <hip/hip_runtime.h>
#include <hip/hip_bf16.h>

typedef __attribute__((ext_vector_type(8))) short short8v;
typedef __attribute__((ext_vector_type(4))) float f32x4;

#define DEVFN __device__ __forceinline__

DEVFN unsigned short f2bf(float x) {
  __hip_bfloat16 h = __float2bfloat16(x);
  return *reinterpret_cast<unsigned short*>(&h);
}

DEVFN float bf2f(unsigned short u) {
  unsigned int x = ((unsigned int)u) << 16;
  float f;
  __builtin_memcpy(&f, &x, 4);
  return f;
}

DEVFN void gload16(const void* g, void* l) {
  __builtin_amdgcn_global_load_lds(
      (const __attribute__((address_space(1))) void*)g,
      (__attribute__((address_space(3))) void*)l, 16, 0, 0);
}

DEVFN short8v pack8(float4 a, float4 b) {
  short8v r;
  r[0] = (short)f2bf(a.x); r[1] = (short)f2bf(a.y);
  r[2] = (short)f2bf(a.z); r[3] = (short)f2bf(a.w);
  r[4] = (short)f2bf(b.x); r[5] = (short)f2bf(b.y);
  r[6] = (short)f2bf(b.z); r[7] = (short)f2bf(b.w);
  return r;
}

// Weight transpose-casts + q_start only (input casts are fused into the GEMMs).
__global__ __launch_bounds__(256) void prep(
    const float* __restrict__ Wk, const float* __restrict__ Wv,
    const float* __restrict__ Wq, const float* __restrict__ Wo,
    const float* __restrict__ Wg,
    unsigned short* __restrict__ Btkv, unsigned short* __restrict__ Btq,
    unsigned short* __restrict__ Bto, unsigned short* __restrict__ Btg,
    const int* __restrict__ q_idx, int* __restrict__ q_start, int Q, int E) {
  const int b = blockIdx.x, t = threadIdx.x;
  if (b < 256) {  // Wk/Wv/Wq/Wo transpose-cast: 64 blocks each
    const int wi = b >> 6, bb = b & 63;
    const float* W = (wi == 0) ? Wk : (wi == 1) ? Wv : (wi == 2) ? Wq : Wo;
    unsigned short* O = (wi == 0) ? Btkv : (wi == 1) ? (Btkv + 65536)
                     : (wi == 2) ? Btq : Bto;
    for (int id = bb * 256 + t; id < 65536; id += 64 * 256) {
      const int n = id >> 8, k = id & 255;
      O[id] = f2bf(W[k * 256 + n]);
    }
  } else if (b < 272) {  // Wg [64][256] -> Btg [256][64]
    for (int id = (b - 256) * 256 + t; id < 16384; id += 16 * 256) {
      const int n = id >> 6, k = id & 63;
      Btg[id] = f2bf(Wg[k * 256 + n]);
    }
  } else {  // q_start: lower_bound over sorted q_idx
    const int q = (b - 272) * 256 + t;
    if (q <= Q) {
      int lo = 0, hi = E;
      while (lo < hi) { int mid = (lo + hi) >> 1; if (q_idx[mid] < q) lo = mid + 1; else hi = mid; }
      q_start[q] = lo;
    }
  }
}

// C = A @ Bt^T. A: fp32 [M][K] (cast in-kernel, reg-staged) or bf16 [M][K]
// (global_load_lds). Bt: bf16 [NB][K]. 128x128 tile, BK=64, 4 waves (2x2),
// each wave 64x64 via 4x4 frags of mfma_f32_16x16x32_bf16.
// LDS chunk swizzle: chunk-slot cs = c ^ (row & 7), applied on both sides.
// OUT_MODE: 0 = fp32, 1 = bf16, at row*ldc+col.
template <bool A_F32, int OUT_MODE, bool HAS_BIAS>
__global__ __launch_bounds__(256) void gemm_mfma(
    const void* __restrict__ Av, const unsigned short* __restrict__ Bt,
    void* __restrict__ Cv, const float* __restrict__ bias, int K, int ldc) {
  __shared__ unsigned short As[128 * 64];
  __shared__ unsigned short Bs[128 * 64];

  const int t = threadIdx.x;
  const int wv = t >> 6, l = t & 63;
  const int wr = wv >> 1, wc = wv & 1;
  const int lr = l & 15, lk = l >> 4;

  // XCD-bijective swizzle (all launches have nwg % 8 == 0)
  const int gx = gridDim.x;
  const int nwg = gx * gridDim.y;
  const int orig = blockIdx.y * gx + blockIdx.x;
  const int cpx = nwg >> 3;
  const int swz = (orig & 7) * cpx + (orig >> 3);
  const int n0 = (swz % gx) * 128;
  const int m0 = (swz / gx) * 128;

  f32x4 acc[4][4];
#pragma unroll
  for (int m = 0; m < 4; ++m)
#pragma unroll
    for (int n = 0; n < 4; ++n) acc[m][n] = (f32x4){0.f, 0.f, 0.f, 0.f};

  const int wbase = (t & ~63) * 16;   // wave-uniform LDS byte base for gload16
  const int arow = t >> 1, cbase = (t & 1) * 4;  // fp32 A staging assignment

  for (int k0 = 0; k0 < K; k0 += 64) {
    if (A_F32) {
      const float* Af = (const float*)Av + (size_t)(m0 + arow) * K + k0;
      float4 fv[8];
#pragma unroll
      for (int j = 0; j < 4; ++j) {
        fv[2 * j]     = *(const float4*)(Af + (cbase + j) * 8);
        fv[2 * j + 1] = *(const float4*)(Af + (cbase + j) * 8 + 4);
      }
#pragma unroll
      for (int j = 0; j < 4; ++j) {
        const int cs = (cbase + j) ^ (arow & 7);
        *(short8v*)&As[arow * 64 + cs * 8] = pack8(fv[2 * j], fv[2 * j + 1]);
      }
    } else {
      const unsigned short* Ab = (const unsigned short*)Av;
#pragma unroll
      for (int s = 0; s < 4; ++s) {
        const int cidx = s * 256 + t;
        const int row = cidx >> 3, c = cidx & 7;
        const int cs = c ^ (row & 7);
        gload16(Ab + (size_t)(m0 + row) * K + k0 + cs * 8,
                (char*)As + (size_t)s * 4096 + wbase);
      }
    }
#pragma unroll
    for (int s = 0; s < 4; ++s) {
      const int cidx = s * 256 + t;
      const int row = cidx >> 3, c = cidx & 7;
      const int cs = c ^ (row & 7);
      gload16(Bt + (size_t)(n0 + row) * K + k0 + cs * 8,
              (char*)Bs + (size_t)s * 4096 + wbase);
    }
    __syncthreads();

#pragma unroll
    for (int kk = 0; kk < 2; ++kk) {
      short8v a[4], b[4];
#pragma unroll
      for (int m = 0; m < 4; ++m) {
        const int row = wr * 64 + m * 16 + lr;
        const int cs = (kk * 4 + lk) ^ (row & 7);
        a[m] = *(const short8v*)&As[row * 64 + cs * 8];
      }
#pragma unroll
      for (int n = 0; n < 4; ++n) {
        const int row = wc * 64 + n * 16 + lr;
        const int cs = (kk * 4 + lk) ^ (row & 7);
        b[n] = *(const short8v*)&Bs[row * 64 + cs * 8];
      }
#pragma unroll
      for (int m = 0; m < 4; ++m)
#pragma unroll
        for (int n = 0; n < 4; ++n)
          acc[m][n] = __builtin_amdgcn_mfma_f32_16x16x32_bf16(a[m], b[n], acc[m][n], 0, 0, 0);
    }
    __syncthreads();
  }

  // epilogue: C/D layout col = lane&15, row = (lane>>4)*4 + reg (m89-verified)
#pragma unroll
  for (int m = 0; m < 4; ++m)
#pragma unroll
    for (int n = 0; n < 4; ++n) {
      const f32x4 v = acc[m][n];
      const int col = n0 + wc * 64 + n * 16 + lr;
      const int rbase = m0 + wr * 64 + m * 16 + lk * 4;
      float bv = 0.f;
      if (HAS_BIAS) bv = bias[col];
#pragma unroll
      for (int r = 0; r < 4; ++r) {
        const float val = v[r] + bv;
        if (OUT_MODE == 0) {
          ((float*)Cv)[(size_t)(rbase + r) * ldc + col] = val;
        } else {
          ((unsigned short*)Cv)[(size_t)(rbase + r) * ldc + col] = f2bf(val);
        }
      }
    }
}

// One block (256 thr = 4 waves) per query; each wave takes every-4th edge.
// 8 lanes per head, 4 dims per lane. KV planar: row = 512 bf16 = K(256)|V(256).
// No online max (exact; scores bounded) -> wave partials merge by summation.
__global__ __launch_bounds__(256) void edge_attn(
    const int* __restrict__ s_idx, const int* __restrict__ q_start,
    const uint2* __restrict__ KV2, const unsigned short* __restrict__ Qf,
    const unsigned short* __restrict__ Gf, unsigned short* __restrict__ out_pre,
    const float* __restrict__ log_tau) {
  const int q = blockIdx.x;
  const int t = threadIdx.x;
  const int w = t >> 6;
  const int lane = t & 63;
  const int start = q_start[q], end = q_start[q + 1];

  const float tau = __expf(log_tau[0]);
  const float rs = 1.0f / (5.656854249492381f * tau);  // 1/(sqrt(32)*tau)

  ushort4 qu = *(const ushort4*)(Qf + (size_t)q * 256 + lane * 4);
  const float qv0 = bf2f(qu.x) * rs, qv1 = bf2f(qu.y) * rs;
  const float qv2 = bf2f(qu.z) * rs, qv3 = bf2f(qu.w) * rs;

  float o0 = 0.f, o1 = 0.f, o2 = 0.f, o3 = 0.f, l = 0.f;

  int i = start + w;
  if (i < end) {
    const uint2* bp = KV2 + (size_t)s_idx[i] * 128;
    uint2 kc = bp[lane], vc = bp[64 + lane];
    for (;;) {
      const int inext = i + 4;
      const bool more = inext < end;
      uint2 kcn, vcn;
      if (more) {
        const uint2* bpn = KV2 + (size_t)s_idx[inext] * 128;
        kcn = bpn[lane];
        vcn = bpn[64 + lane];
      }
      const float k0 = bf2f((unsigned short)(kc.x & 0xffffu));
      const float k1 = bf2f((unsigned short)(kc.x >> 16));
      const float k2 = bf2f((unsigned short)(kc.y & 0xffffu));
      const float k3 = bf2f((unsigned short)(kc.y >> 16));
      const float v0 = bf2f((unsigned short)(vc.x & 0xffffu));
      const float v1 = bf2f((unsigned short)(vc.x >> 16));
      const float v2 = bf2f((unsigned short)(vc.y & 0xffffu));
      const float v3 = bf2f((unsigned short)(vc.y >> 16));
      float p = qv0 * k0 + qv1 * k1 + qv2 * k2 + qv3 * k3;
      p += __shfl_xor(p, 1);
      p += __shfl_xor(p, 2);
      p += __shfl_xor(p, 4);   // full head dot for this edge
      const float ew = __expf(p);
      l += ew;
      o0 = fmaf(ew, v0, o0);
      o1 = fmaf(ew, v1, o1);
      o2 = fmaf(ew, v2, o2);
      o3 = fmaf(ew, v3, o3);
      if (!more) break;
      i = inext;
      kc = kcn;
      vc = vcn;
    }
  }

  __shared__ float o_sh[4][256];
  __shared__ float l_sh[4][8];
  *(float4*)&o_sh[w][lane * 4] = (float4){o0, o1, o2, o3};
  if ((lane & 7) == 0) l_sh[w][lane >> 3] = l;
  __syncthreads();

  const float osum = o_sh[0][t] + o_sh[1][t] + o_sh[2][t] + o_sh[3][t];
  const int h = t >> 5;
  const float lsum = l_sh[0][h] + l_sh[1][h] + l_sh[2][h] + l_sh[3][h];
  const float inv = 1.0f / fmaxf(lsum, 1e-8f);
  float res = 0.f;
  if (end > start) res = osum * inv + (lsum * inv) * bf2f(Gf[(size_t)q * 256 + t]);
  out_pre[(size_t)q * 256 + t] = f2bf(res);
}

extern "C" void kernel_launch(void* const* d_in, const int* in_sizes, int n_in,
                              void* d_out, int out_size, void* d_ws, size_t ws_size,
                              hipStream_t stream) {
  const float* query   = (const float*)d_in[0];
  const float* support = (const float*)d_in[1];
  const float* geo     = (const float*)d_in[2];
  const int*   q_idx   = (const int*)d_in[3];
  const int*   s_idx   = (const int*)d_in[4];
  const float* Wq      = (const float*)d_in[6];
  const float* Wk      = (const float*)d_in[7];
  const float* Wv      = (const float*)d_in[8];
  const float* Wg      = (const float*)d_in[9];
  const float* Wo      = (const float*)d_in[10];
  const float* bo      = (const float*)d_in[11];
  const float* log_tau = (const float*)d_in[12];

  const int D = 256;
  const int Q = in_sizes[0] / D;   // 8192
  const int N = in_sizes[1] / D;   // 65536
  const int E = in_sizes[3];       // 262144

  unsigned short* ws = (unsigned short*)d_ws;
  unsigned short* KV   = ws;                       // [N][512] bf16 planar K|V
  unsigned short* Qf   = KV   + (size_t)N * 512;   // bf16 [Q][256]
  unsigned short* Gf   = Qf   + (size_t)Q * 256;   // bf16 [Q][256]
  unsigned short* Opre = Gf   + (size_t)Q * 256;   // bf16 [Q][256]
  unsigned short* Btkv = Opre + (size_t)Q * 256;   // [512][256] = [Wk^T; Wv^T]
  unsigned short* Btq  = Btkv + 512 * 256;         // [256][256]
  unsigned short* Btg  = Btq  + 256 * 256;         // [256][64]
  unsigned short* Bto  = Btg  + 256 * 64;          // [256][256]
  int* q_start = (int*)(Bto + 256 * 256);          // [Q+1]

  dim3 blk(256);

  prep<<<dim3(305), blk, 0, stream>>>(Wk, Wv, Wq, Wo, Wg,
                                      Btkv, Btq, Bto, Btg, q_idx, q_start, Q, E);

  // KV projection (fused fp32 A cast), planar K|V output
  gemm_mfma<true, 1, false><<<dim3(4, N / 128), blk, 0, stream>>>(
      support, Btkv, (void*)KV, nullptr, D, 512);
  gemm_mfma<true, 1, false><<<dim3(2, Q / 128), blk, 0, stream>>>(
      query, Btq, (void*)Qf, nullptr, D, D);
  gemm_mfma<true, 1, false><<<dim3(2, Q / 128), blk, 0, stream>>>(
      geo, Btg, (void*)Gf, nullptr, 64, D);

  edge_attn<<<dim3(Q), blk, 0, stream>>>(s_idx, q_start, (const uint2*)KV,
                                         Qf, Gf, Opre, log_tau);

  gemm_mfma<false, 0, true><<<dim3(2, Q / 128), blk, 0, stream>>>(
      Opre, Bto, d_out, bo, D, D);
}

// Round 5
// 109.067 us; speedup vs baseline: 1.2183x; 1.2183x over previous
//
#include <hip/hip_runtime.h>
#include <hip/hip_bf16.h>

typedef __attribute__((ext_vector_type(8))) short short8v;
typedef __attribute__((ext_vector_type(4))) float f32x4;

#define DEVFN __device__ __forceinline__

DEVFN unsigned short f2bf(float x) {
  __hip_bfloat16 h = __float2bfloat16(x);
  return *reinterpret_cast<unsigned short*>(&h);
}

DEVFN float bf2f(unsigned short u) {
  unsigned int x = ((unsigned int)u) << 16;
  float f;
  __builtin_memcpy(&f, &x, 4);
  return f;
}

DEVFN void gload16(const void* g, void* l) {
  __builtin_amdgcn_global_load_lds(
      (const __attribute__((address_space(1))) void*)g,
      (__attribute__((address_space(3))) void*)l, 16, 0, 0);
}

// Weight transpose-casts + q_start only (input casts fused into the GEMMs).
__global__ __launch_bounds__(256) void prep(
    const float* __restrict__ Wk, const float* __restrict__ Wv,
    const float* __restrict__ Wq, const float* __restrict__ Wo,
    const float* __restrict__ Wg,
    unsigned short* __restrict__ Btkv, unsigned short* __restrict__ Btq,
    unsigned short* __restrict__ Bto, unsigned short* __restrict__ Btg,
    const int* __restrict__ q_idx, int* __restrict__ q_start, int Q, int E) {
  const int b = blockIdx.x, t = threadIdx.x;
  if (b < 256) {  // Wk/Wv/Wq/Wo transpose-cast: 64 blocks each
    const int wi = b >> 6, bb = b & 63;
    const float* W = (wi == 0) ? Wk : (wi == 1) ? Wv : (wi == 2) ? Wq : Wo;
    unsigned short* O = (wi == 0) ? Btkv : (wi == 1) ? (Btkv + 65536)
                     : (wi == 2) ? Btq : Bto;
    for (int id = bb * 256 + t; id < 65536; id += 64 * 256) {
      const int n = id >> 8, k = id & 255;
      O[id] = f2bf(W[k * 256 + n]);
    }
  } else if (b < 272) {  // Wg [64][256] -> Btg [256][64]
    for (int id = (b - 256) * 256 + t; id < 16384; id += 16 * 256) {
      const int n = id >> 6, k = id & 63;
      Btg[id] = f2bf(Wg[k * 256 + n]);
    }
  } else {  // q_start: lower_bound over sorted q_idx
    const int q = (b - 272) * 256 + t;
    if (q <= Q) {
      int lo = 0, hi = E;
      while (lo < hi) { int mid = (lo + hi) >> 1; if (q_idx[mid] < q) lo = mid + 1; else hi = mid; }
      q_start[q] = lo;
    }
  }
}

// C = A @ Bt^T. A: fp32 [M][K] staged RAW into LDS via global_load_lds,
// converted fp32->bf16 at the LDS->fragment read; or bf16 [M][K] (direct).
// Bt: bf16 [NB][K]. 128x128 tile, BK=32, 4 waves (2x2), 4x4 frags of
// mfma_f32_16x16x32_bf16 per wave. Chunk-XOR swizzle on both sides (rule 21).
// OUT_MODE: 0 = fp32, 1 = bf16, at row*ldc+col.
template <bool A_F32, int OUT_MODE, bool HAS_BIAS>
__global__ __launch_bounds__(256) void gemm_mfma(
    const void* __restrict__ Av, const unsigned short* __restrict__ Bt,
    void* __restrict__ Cv, const float* __restrict__ bias, int K, int ldc) {
  __shared__ char AsRaw[16384];           // fp32: [128][32] f32; bf16: [128][32] u16 (8KB)
  __shared__ unsigned short Bs[128 * 32]; // 8 KB

  const int t = threadIdx.x;
  const int wv = t >> 6, l = t & 63;
  const int wr = wv >> 1, wc = wv & 1;
  const int lr = l & 15, lk = l >> 4;

  // XCD-bijective swizzle (all launches have nwg % 8 == 0)
  const int gx = gridDim.x;
  const int nwg = gx * gridDim.y;
  const int orig = blockIdx.y * gx + blockIdx.x;
  const int cpx = nwg >> 3;
  const int swz = (orig & 7) * cpx + (orig >> 3);
  const int n0 = (swz % gx) * 128;
  const int m0 = (swz / gx) * 128;

  f32x4 acc[4][4];
#pragma unroll
  for (int m = 0; m < 4; ++m)
#pragma unroll
    for (int n = 0; n < 4; ++n) acc[m][n] = (f32x4){0.f, 0.f, 0.f, 0.f};

  const int wbase = (t & ~63) * 16;  // wave-uniform LDS byte base for gload16

  for (int k0 = 0; k0 < K; k0 += 32) {
    if (A_F32) {
      // A tile 128x32 fp32 = 16 KB: row = 8 chunks of 4 floats, cs = c^(row&7)
      const float* Af = (const float*)Av;
#pragma unroll
      for (int s = 0; s < 4; ++s) {
        const int cidx = s * 256 + t;
        const int row = cidx >> 3, c = cidx & 7;
        const int cs = c ^ (row & 7);
        gload16(Af + (size_t)(m0 + row) * K + k0 + cs * 4,
                AsRaw + (size_t)s * 4096 + wbase);
      }
    } else {
      // A tile 128x32 bf16 = 8 KB: row = 4 chunks of 8 bf16, cs = c^((row>>1)&3)
      const unsigned short* Ab = (const unsigned short*)Av;
#pragma unroll
      for (int s = 0; s < 2; ++s) {
        const int cidx = s * 256 + t;
        const int row = cidx >> 2, c = cidx & 3;
        const int cs = c ^ ((row >> 1) & 3);
        gload16(Ab + (size_t)(m0 + row) * K + k0 + cs * 8,
                AsRaw + (size_t)s * 4096 + wbase);
      }
    }
#pragma unroll
    for (int s = 0; s < 2; ++s) {
      const int cidx = s * 256 + t;
      const int row = cidx >> 2, c = cidx & 3;
      const int cs = c ^ ((row >> 1) & 3);
      gload16(Bt + (size_t)(n0 + row) * K + k0 + cs * 8,
              (char*)Bs + (size_t)s * 4096 + wbase);
    }
    __syncthreads();

    short8v a[4], b[4];
#pragma unroll
    for (int m = 0; m < 4; ++m) {
      const int row = wr * 64 + m * 16 + lr;
      if (A_F32) {
        const float* Asf = (const float*)AsRaw;
        const int slotA = (2 * lk) ^ (row & 7);
        const int slotB = (2 * lk + 1) ^ (row & 7);
        f32x4 lo = *(const f32x4*)&Asf[row * 32 + slotA * 4];
        f32x4 hi = *(const f32x4*)&Asf[row * 32 + slotB * 4];
        short8v r;
        r[0] = (short)f2bf(lo[0]); r[1] = (short)f2bf(lo[1]);
        r[2] = (short)f2bf(lo[2]); r[3] = (short)f2bf(lo[3]);
        r[4] = (short)f2bf(hi[0]); r[5] = (short)f2bf(hi[1]);
        r[6] = (short)f2bf(hi[2]); r[7] = (short)f2bf(hi[3]);
        a[m] = r;
      } else {
        const unsigned short* Asb = (const unsigned short*)AsRaw;
        const int cs = lk ^ ((row >> 1) & 3);
        a[m] = *(const short8v*)&Asb[row * 32 + cs * 8];
      }
    }
#pragma unroll
    for (int n = 0; n < 4; ++n) {
      const int row = wc * 64 + n * 16 + lr;
      const int cs = lk ^ ((row >> 1) & 3);
      b[n] = *(const short8v*)&Bs[row * 32 + cs * 8];
    }
#pragma unroll
    for (int m = 0; m < 4; ++m)
#pragma unroll
      for (int n = 0; n < 4; ++n)
        acc[m][n] = __builtin_amdgcn_mfma_f32_16x16x32_bf16(a[m], b[n], acc[m][n], 0, 0, 0);
    __syncthreads();
  }

  // epilogue: C/D layout col = lane&15, row = (lane>>4)*4 + reg (m89-verified)
#pragma unroll
  for (int m = 0; m < 4; ++m)
#pragma unroll
    for (int n = 0; n < 4; ++n) {
      const f32x4 v = acc[m][n];
      const int col = n0 + wc * 64 + n * 16 + lr;
      const int rbase = m0 + wr * 64 + m * 16 + lk * 4;
      float bv = 0.f;
      if (HAS_BIAS) bv = bias[col];
#pragma unroll
      for (int r = 0; r < 4; ++r) {
        const float val = v[r] + bv;
        if (OUT_MODE == 0) {
          ((float*)Cv)[(size_t)(rbase + r) * ldc + col] = val;
        } else {
          ((unsigned short*)Cv)[(size_t)(rbase + r) * ldc + col] = f2bf(val);
        }
      }
    }
}

// One block (256 thr) per query. 8 edge streams per block: stream =
// wave*2 + (lane>=32), 32 lanes per edge, 8 dims per lane (uint4 = 8 bf16).
// KV planar: row = 512 bf16 = K(256)|V(256). s_idx staged in LDS; rolling
// depth-1 KV prefetch per stream. No online max (exact; scores bounded) ->
// stream partials merge by summation.
__global__ __launch_bounds__(256) void edge_attn(
    const int* __restrict__ s_idx, const int* __restrict__ q_start,
    const uint4* __restrict__ KV4, const unsigned short* __restrict__ Qf,
    const unsigned short* __restrict__ Gf, unsigned short* __restrict__ out_pre,
    const float* __restrict__ log_tau) {
  const int q = blockIdx.x;
  const int t = threadIdx.x;
  const int w = t >> 6;
  const int lane = t & 63;
  const int stream = w * 2 + (lane >> 5);  // 0..7
  const int sl = lane & 31;                // lane within edge
  const int start = q_start[q], end = q_start[q + 1];

  const float tau = __expf(log_tau[0]);
  const float rs = 1.0f / (5.656854249492381f * tau);  // 1/(sqrt(32)*tau)

  // q dims sl*8..sl*8+7, pre-scaled
  float qv[8];
  {
    uint4 qw = *(const uint4*)(Qf + (size_t)q * 256 + sl * 8);
    const unsigned int ws_[4] = {qw.x, qw.y, qw.z, qw.w};
#pragma unroll
    for (int j = 0; j < 4; ++j) {
      qv[2 * j]     = bf2f((unsigned short)(ws_[j] & 0xffffu)) * rs;
      qv[2 * j + 1] = bf2f((unsigned short)(ws_[j] >> 16)) * rs;
    }
  }

  float o[8];
#pragma unroll
  for (int j = 0; j < 8; ++j) o[j] = 0.f;
  float lsum_p = 0.f;

  __shared__ int sseg[1024];

  for (int cb = start; cb < end; cb += 1024) {
    const int nb = min(1024, end - cb);
    __syncthreads();
    for (int jj = t; jj < nb; jj += 256) sseg[jj] = s_idx[cb + jj];
    __syncthreads();

    int j = stream;
    uint4 kc, vc;
    if (j < nb) {
      const uint4* bp = KV4 + (size_t)sseg[j] * 64;
      kc = bp[sl];
      vc = bp[32 + sl];
    }
    while (j < nb) {
      const int jn = j + 8;
      const bool more = jn < nb;
      uint4 kcn, vcn;
      if (more) {
        const uint4* bpn = KV4 + (size_t)sseg[jn] * 64;
        kcn = bpn[sl];
        vcn = bpn[32 + sl];
      }
      const unsigned int kw[4] = {kc.x, kc.y, kc.z, kc.w};
      float p = 0.f;
#pragma unroll
      for (int jj = 0; jj < 4; ++jj) {
        p = fmaf(qv[2 * jj], bf2f((unsigned short)(kw[jj] & 0xffffu)), p);
        p = fmaf(qv[2 * jj + 1], bf2f((unsigned short)(kw[jj] >> 16)), p);
      }
      p += __shfl_xor(p, 1);
      p += __shfl_xor(p, 2);   // full 32-dim head dot (4-lane group)
      const float ew = __expf(p);
      lsum_p += ew;
      const unsigned int vw[4] = {vc.x, vc.y, vc.z, vc.w};
#pragma unroll
      for (int jj = 0; jj < 4; ++jj) {
        o[2 * jj]     = fmaf(ew, bf2f((unsigned short)(vw[jj] & 0xffffu)), o[2 * jj]);
        o[2 * jj + 1] = fmaf(ew, bf2f((unsigned short)(vw[jj] >> 16)), o[2 * jj + 1]);
      }
      j = jn;
      kc = kcn;
      vc = vcn;
    }
  }

  __shared__ float o_sh[8][256];
  __shared__ float l_sh[8][8];
  *(float4*)&o_sh[stream][sl * 8]     = (float4){o[0], o[1], o[2], o[3]};
  *(float4*)&o_sh[stream][sl * 8 + 4] = (float4){o[4], o[5], o[6], o[7]};
  if ((sl & 3) == 0) l_sh[stream][sl >> 2] = lsum_p;
  __syncthreads();

  float osum = 0.f, lsum = 0.f;
  const int h = t >> 5;
#pragma unroll
  for (int s = 0; s < 8; ++s) {
    osum += o_sh[s][t];
    lsum += l_sh[s][h];
  }
  const float inv = 1.0f / fmaxf(lsum, 1e-8f);
  float res = 0.f;
  if (end > start) res = osum * inv + (lsum * inv) * bf2f(Gf[(size_t)q * 256 + t]);
  out_pre[(size_t)q * 256 + t] = f2bf(res);
}

extern "C" void kernel_launch(void* const* d_in, const int* in_sizes, int n_in,
                              void* d_out, int out_size, void* d_ws, size_t ws_size,
                              hipStream_t stream) {
  const float* query   = (const float*)d_in[0];
  const float* support = (const float*)d_in[1];
  const float* geo     = (const float*)d_in[2];
  const int*   q_idx   = (const int*)d_in[3];
  const int*   s_idx   = (const int*)d_in[4];
  const float* Wq      = (const float*)d_in[6];
  const float* Wk      = (const float*)d_in[7];
  const float* Wv      = (const float*)d_in[8];
  const float* Wg      = (const float*)d_in[9];
  const float* Wo      = (const float*)d_in[10];
  const float* bo      = (const float*)d_in[11];
  const float* log_tau = (const float*)d_in[12];

  const int D = 256;
  const int Q = in_sizes[0] / D;   // 8192
  const int N = in_sizes[1] / D;   // 65536
  const int E = in_sizes[3];       // 262144

  unsigned short* ws = (unsigned short*)d_ws;
  unsigned short* KV   = ws;                       // [N][512] bf16 planar K|V
  unsigned short* Qf   = KV   + (size_t)N * 512;   // bf16 [Q][256]
  unsigned short* Gf   = Qf   + (size_t)Q * 256;   // bf16 [Q][256]
  unsigned short* Opre = Gf   + (size_t)Q * 256;   // bf16 [Q][256]
  unsigned short* Btkv = Opre + (size_t)Q * 256;   // [512][256] = [Wk^T; Wv^T]
  unsigned short* Btq  = Btkv + 512 * 256;         // [256][256]
  unsigned short* Btg  = Btq  + 256 * 256;         // [256][64]
  unsigned short* Bto  = Btg  + 256 * 64;          // [256][256]
  int* q_start = (int*)(Bto + 256 * 256);          // [Q+1]

  dim3 blk(256);

  prep<<<dim3(305), blk, 0, stream>>>(Wk, Wv, Wq, Wo, Wg,
                                      Btkv, Btq, Bto, Btg, q_idx, q_start, Q, E);

  // KV projection (fp32 A staged raw, converted at LDS->reg), planar K|V out
  gemm_mfma<true, 1, false><<<dim3(4, N / 128), blk, 0, stream>>>(
      support, Btkv, (void*)KV, nullptr, D, 512);
  gemm_mfma<true, 1, false><<<dim3(2, Q / 128), blk, 0, stream>>>(
      query, Btq, (void*)Qf, nullptr, D, D);
  gemm_mfma<true, 1, false><<<dim3(2, Q / 128), blk, 0, stream>>>(
      geo, Btg, (void*)Gf, nullptr, 64, D);

  edge_attn<<<dim3(Q), blk, 0, stream>>>(s_idx, q_start, (const uint4*)KV,
                                         Qf, Gf, Opre, log_tau);

  gemm_mfma<false, 0, true><<<dim3(2, Q / 128), blk, 0, stream>>>(
      Opre, Bto, d_out, bo, D, D);
}

// Round 6
// 102.917 us; speedup vs baseline: 1.2911x; 1.0598x over previous
//
#include <hip/hip_runtime.h>
#include <hip/hip_bf16.h>

typedef __attribute__((ext_vector_type(8))) short short8v;
typedef __attribute__((ext_vector_type(4))) float f32x4;

#define DEVFN __device__ __forceinline__

DEVFN unsigned short f2bf(float x) {
  __hip_bfloat16 h = __float2bfloat16(x);
  return *reinterpret_cast<unsigned short*>(&h);
}

DEVFN float bf2f(unsigned short u) {
  unsigned int x = ((unsigned int)u) << 16;
  float f;
  __builtin_memcpy(&f, &x, 4);
  return f;
}

DEVFN void gload16(const void* g, void* l) {
  __builtin_amdgcn_global_load_lds(
      (const __attribute__((address_space(1))) void*)g,
      (__attribute__((address_space(3))) void*)l, 16, 0, 0);
}

// Weight transpose-casts + q_start only (input casts fused into the GEMMs).
__global__ __launch_bounds__(256) void prep(
    const float* __restrict__ Wk, const float* __restrict__ Wv,
    const float* __restrict__ Wq, const float* __restrict__ Wo,
    const float* __restrict__ Wg,
    unsigned short* __restrict__ Btkv, unsigned short* __restrict__ Btq,
    unsigned short* __restrict__ Bto, unsigned short* __restrict__ Btg,
    const int* __restrict__ q_idx, int* __restrict__ q_start, int Q, int E) {
  const int b = blockIdx.x, t = threadIdx.x;
  if (b < 256) {  // Wk/Wv/Wq/Wo transpose-cast: 64 blocks each
    const int wi = b >> 6, bb = b & 63;
    const float* W = (wi == 0) ? Wk : (wi == 1) ? Wv : (wi == 2) ? Wq : Wo;
    unsigned short* O = (wi == 0) ? Btkv : (wi == 1) ? (Btkv + 65536)
                     : (wi == 2) ? Btq : Bto;
    for (int id = bb * 256 + t; id < 65536; id += 64 * 256) {
      const int n = id >> 8, k = id & 255;
      O[id] = f2bf(W[k * 256 + n]);
    }
  } else if (b < 272) {  // Wg [64][256] -> Btg [256][64]
    for (int id = (b - 256) * 256 + t; id < 16384; id += 16 * 256) {
      const int n = id >> 6, k = id & 63;
      Btg[id] = f2bf(Wg[k * 256 + n]);
    }
  } else {  // q_start: lower_bound over sorted q_idx
    const int q = (b - 272) * 256 + t;
    if (q <= Q) {
      int lo = 0, hi = E;
      while (lo < hi) { int mid = (lo + hi) >> 1; if (q_idx[mid] < q) lo = mid + 1; else hi = mid; }
      q_start[q] = lo;
    }
  }
}

// C = A @ Bt^T. A: fp32 [M][K] staged RAW into LDS (converted at LDS->frag
// read) or bf16 [M][K]. Bt: bf16 [NB][K]. 128x128 tile, BK=32, 4 waves (2x2),
// 4x4 frags of mfma_f32_16x16x32_bf16 per wave.
// 2-phase double-buffered pipeline: stage(t+1) issued BEFORE compute(t);
// counted s_waitcnt vmcnt(N) + raw s_barrier (never vmcnt(0) in the loop).
// Chunk-XOR swizzle on both sides (rule 21). OUT_MODE: 0 = fp32, 1 = bf16.
template <bool A_F32, int OUT_MODE, bool HAS_BIAS>
__global__ __launch_bounds__(256) void gemm_mfma(
    const void* __restrict__ Av, const unsigned short* __restrict__ Bt,
    void* __restrict__ Cv, const float* __restrict__ bias, int K, int ldc) {
  constexpr int ABYTES = A_F32 ? 16384 : 8192;
  __shared__ char AsRaw[2][ABYTES];
  __shared__ unsigned short Bs[2][128 * 32];

  const int t = threadIdx.x;
  const int wv = t >> 6, l = t & 63;
  const int wr = wv >> 1, wc = wv & 1;
  const int lr = l & 15, lk = l >> 4;

  // XCD-bijective swizzle (all launches have nwg % 8 == 0)
  const int gx = gridDim.x;
  const int nwg = gx * gridDim.y;
  const int orig = blockIdx.y * gx + blockIdx.x;
  const int cpx = nwg >> 3;
  const int swz = (orig & 7) * cpx + (orig >> 3);
  const int n0 = (swz % gx) * 128;
  const int m0 = (swz / gx) * 128;

  f32x4 acc[4][4];
#pragma unroll
  for (int m = 0; m < 4; ++m)
#pragma unroll
    for (int n = 0; n < 4; ++n) acc[m][n] = (f32x4){0.f, 0.f, 0.f, 0.f};

  const int wbase = (t & ~63) * 16;  // wave-uniform LDS byte base for gload16

  auto stage = [&](int buf, int k0) {
    if (A_F32) {
      const float* Af = (const float*)Av;
#pragma unroll
      for (int s = 0; s < 4; ++s) {
        const int cidx = s * 256 + t;
        const int row = cidx >> 3, c = cidx & 7;
        const int cs = c ^ (row & 7);
        gload16(Af + (size_t)(m0 + row) * K + k0 + cs * 4,
                &AsRaw[buf][s * 4096 + wbase]);
      }
    } else {
      const unsigned short* Ab = (const unsigned short*)Av;
#pragma unroll
      for (int s = 0; s < 2; ++s) {
        const int cidx = s * 256 + t;
        const int row = cidx >> 2, c = cidx & 3;
        const int cs = c ^ ((row >> 1) & 3);
        gload16(Ab + (size_t)(m0 + row) * K + k0 + cs * 8,
                &AsRaw[buf][s * 4096 + wbase]);
      }
    }
#pragma unroll
    for (int s = 0; s < 2; ++s) {
      const int cidx = s * 256 + t;
      const int row = cidx >> 2, c = cidx & 3;
      const int cs = c ^ ((row >> 1) & 3);
      gload16(Bt + (size_t)(n0 + row) * K + k0 + cs * 8,
              (char*)&Bs[buf][0] + (size_t)s * 4096 + wbase);
    }
  };

  auto compute = [&](int buf) {
    short8v a[4], b[4];
#pragma unroll
    for (int m = 0; m < 4; ++m) {
      const int row = wr * 64 + m * 16 + lr;
      if (A_F32) {
        const float* Asf = (const float*)&AsRaw[buf][0];
        const int slotA = (2 * lk) ^ (row & 7);
        const int slotB = (2 * lk + 1) ^ (row & 7);
        f32x4 lo = *(const f32x4*)&Asf[row * 32 + slotA * 4];
        f32x4 hi = *(const f32x4*)&Asf[row * 32 + slotB * 4];
        short8v r;
        r[0] = (short)f2bf(lo[0]); r[1] = (short)f2bf(lo[1]);
        r[2] = (short)f2bf(lo[2]); r[3] = (short)f2bf(lo[3]);
        r[4] = (short)f2bf(hi[0]); r[5] = (short)f2bf(hi[1]);
        r[6] = (short)f2bf(hi[2]); r[7] = (short)f2bf(hi[3]);
        a[m] = r;
      } else {
        const unsigned short* Asb = (const unsigned short*)&AsRaw[buf][0];
        const int cs = lk ^ ((row >> 1) & 3);
        a[m] = *(const short8v*)&Asb[row * 32 + cs * 8];
      }
    }
#pragma unroll
    for (int n = 0; n < 4; ++n) {
      const int row = wc * 64 + n * 16 + lr;
      const int cs = lk ^ ((row >> 1) & 3);
      b[n] = *(const short8v*)&Bs[buf][row * 32 + cs * 8];
    }
#pragma unroll
    for (int m = 0; m < 4; ++m)
#pragma unroll
      for (int n = 0; n < 4; ++n)
        acc[m][n] = __builtin_amdgcn_mfma_f32_16x16x32_bf16(a[m], b[n], acc[m][n], 0, 0, 0);
  };

  const int nt = K >> 5;
  stage(0, 0);
  for (int tt = 0; tt < nt - 1; ++tt) {
    stage((tt + 1) & 1, (tt + 1) * 32);          // prefetch next tile
    if (A_F32)
      asm volatile("s_waitcnt vmcnt(6)");         // current tile's 6 loads done
    else
      asm volatile("s_waitcnt vmcnt(4)");         // current tile's 4 loads done
    __builtin_amdgcn_s_barrier();
    __builtin_amdgcn_sched_barrier(0);
    compute(tt & 1);
    __builtin_amdgcn_s_barrier();                 // readers done before overwrite
    __builtin_amdgcn_sched_barrier(0);
  }
  asm volatile("s_waitcnt vmcnt(0)");
  __builtin_amdgcn_s_barrier();
  __builtin_amdgcn_sched_barrier(0);
  compute((nt - 1) & 1);

  // epilogue: C/D layout col = lane&15, row = (lane>>4)*4 + reg (m89-verified)
#pragma unroll
  for (int m = 0; m < 4; ++m)
#pragma unroll
    for (int n = 0; n < 4; ++n) {
      const f32x4 v = acc[m][n];
      const int col = n0 + wc * 64 + n * 16 + lr;
      const int rbase = m0 + wr * 64 + m * 16 + lk * 4;
      float bv = 0.f;
      if (HAS_BIAS) bv = bias[col];
#pragma unroll
      for (int r = 0; r < 4; ++r) {
        const float val = v[r] + bv;
        if (OUT_MODE == 0) {
          ((float*)Cv)[(size_t)(rbase + r) * ldc + col] = val;
        } else {
          ((unsigned short*)Cv)[(size_t)(rbase + r) * ldc + col] = f2bf(val);
        }
      }
    }
}

// One block (256 thr) per query. 8 edge streams per block: stream =
// wave*2 + (lane>=32), 32 lanes per edge, 8 dims per lane (uint4 = 8 bf16).
// KV planar: row = 512 bf16 = K(256)|V(256). s_idx staged in LDS; rolling
// depth-1 KV prefetch per stream. No online max (exact; scores bounded) ->
// stream partials merge by summation.
__global__ __launch_bounds__(256) void edge_attn(
    const int* __restrict__ s_idx, const int* __restrict__ q_start,
    const uint4* __restrict__ KV4, const unsigned short* __restrict__ Qf,
    const unsigned short* __restrict__ Gf, unsigned short* __restrict__ out_pre,
    const float* __restrict__ log_tau) {
  const int q = blockIdx.x;
  const int t = threadIdx.x;
  const int w = t >> 6;
  const int lane = t & 63;
  const int stream = w * 2 + (lane >> 5);  // 0..7
  const int sl = lane & 31;                // lane within edge
  const int start = q_start[q], end = q_start[q + 1];

  const float tau = __expf(log_tau[0]);
  const float rs = 1.0f / (5.656854249492381f * tau);  // 1/(sqrt(32)*tau)

  float qv[8];
  {
    uint4 qw = *(const uint4*)(Qf + (size_t)q * 256 + sl * 8);
    const unsigned int ws_[4] = {qw.x, qw.y, qw.z, qw.w};
#pragma unroll
    for (int j = 0; j < 4; ++j) {
      qv[2 * j]     = bf2f((unsigned short)(ws_[j] & 0xffffu)) * rs;
      qv[2 * j + 1] = bf2f((unsigned short)(ws_[j] >> 16)) * rs;
    }
  }

  float o[8];
#pragma unroll
  for (int j = 0; j < 8; ++j) o[j] = 0.f;
  float lsum_p = 0.f;

  __shared__ int sseg[1024];

  for (int cb = start; cb < end; cb += 1024) {
    const int nb = min(1024, end - cb);
    __syncthreads();
    for (int jj = t; jj < nb; jj += 256) sseg[jj] = s_idx[cb + jj];
    __syncthreads();

    int j = stream;
    uint4 kc, vc;
    if (j < nb) {
      const uint4* bp = KV4 + (size_t)sseg[j] * 64;
      kc = bp[sl];
      vc = bp[32 + sl];
    }
    while (j < nb) {
      const int jn = j + 8;
      const bool more = jn < nb;
      uint4 kcn, vcn;
      if (more) {
        const uint4* bpn = KV4 + (size_t)sseg[jn] * 64;
        kcn = bpn[sl];
        vcn = bpn[32 + sl];
      }
      const unsigned int kw[4] = {kc.x, kc.y, kc.z, kc.w};
      float p = 0.f;
#pragma unroll
      for (int jj = 0; jj < 4; ++jj) {
        p = fmaf(qv[2 * jj], bf2f((unsigned short)(kw[jj] & 0xffffu)), p);
        p = fmaf(qv[2 * jj + 1], bf2f((unsigned short)(kw[jj] >> 16)), p);
      }
      p += __shfl_xor(p, 1);
      p += __shfl_xor(p, 2);   // full 32-dim head dot (4-lane group)
      const float ew = __expf(p);
      lsum_p += ew;
      const unsigned int vw[4] = {vc.x, vc.y, vc.z, vc.w};
#pragma unroll
      for (int jj = 0; jj < 4; ++jj) {
        o[2 * jj]     = fmaf(ew, bf2f((unsigned short)(vw[jj] & 0xffffu)), o[2 * jj]);
        o[2 * jj + 1] = fmaf(ew, bf2f((unsigned short)(vw[jj] >> 16)), o[2 * jj + 1]);
      }
      j = jn;
      kc = kcn;
      vc = vcn;
    }
  }

  __shared__ float o_sh[8][256];
  __shared__ float l_sh[8][8];
  *(float4*)&o_sh[stream][sl * 8]     = (float4){o[0], o[1], o[2], o[3]};
  *(float4*)&o_sh[stream][sl * 8 + 4] = (float4){o[4], o[5], o[6], o[7]};
  if ((sl & 3) == 0) l_sh[stream][sl >> 2] = lsum_p;
  __syncthreads();

  float osum = 0.f, lsum = 0.f;
  const int h = t >> 5;
#pragma unroll
  for (int s = 0; s < 8; ++s) {
    osum += o_sh[s][t];
    lsum += l_sh[s][h];
  }
  const float inv = 1.0f / fmaxf(lsum, 1e-8f);
  float res = 0.f;
  if (end > start) res = osum * inv + (lsum * inv) * bf2f(Gf[(size_t)q * 256 + t]);
  out_pre[(size_t)q * 256 + t] = f2bf(res);
}

extern "C" void kernel_launch(void* const* d_in, const int* in_sizes, int n_in,
                              void* d_out, int out_size, void* d_ws, size_t ws_size,
                              hipStream_t stream) {
  const float* query   = (const float*)d_in[0];
  const float* support = (const float*)d_in[1];
  const float* geo     = (const float*)d_in[2];
  const int*   q_idx   = (const int*)d_in[3];
  const int*   s_idx   = (const int*)d_in[4];
  const float* Wq      = (const float*)d_in[6];
  const float* Wk      = (const float*)d_in[7];
  const float* Wv      = (const float*)d_in[8];
  const float* Wg      = (const float*)d_in[9];
  const float* Wo      = (const float*)d_in[10];
  const float* bo      = (const float*)d_in[11];
  const float* log_tau = (const float*)d_in[12];

  const int D = 256;
  const int Q = in_sizes[0] / D;   // 8192
  const int N = in_sizes[1] / D;   // 65536
  const int E = in_sizes[3];       // 262144

  unsigned short* ws = (unsigned short*)d_ws;
  unsigned short* KV   = ws;                       // [N][512] bf16 planar K|V
  unsigned short* Qf   = KV   + (size_t)N * 512;   // bf16 [Q][256]
  unsigned short* Gf   = Qf   + (size_t)Q * 256;   // bf16 [Q][256]
  unsigned short* Opre = Gf   + (size_t)Q * 256;   // bf16 [Q][256]
  unsigned short* Btkv = Opre + (size_t)Q * 256;   // [512][256] = [Wk^T; Wv^T]
  unsigned short* Btq  = Btkv + 512 * 256;         // [256][256]
  unsigned short* Btg  = Btq  + 256 * 256;         // [256][64]
  unsigned short* Bto  = Btg  + 256 * 64;          // [256][256]
  int* q_start = (int*)(Bto + 256 * 256);          // [Q+1]

  dim3 blk(256);

  prep<<<dim3(305), blk, 0, stream>>>(Wk, Wv, Wq, Wo, Wg,
                                      Btkv, Btq, Bto, Btg, q_idx, q_start, Q, E);

  // KV projection (fp32 A staged raw, converted at LDS->reg), planar K|V out
  gemm_mfma<true, 1, false><<<dim3(4, N / 128), blk, 0, stream>>>(
      support, Btkv, (void*)KV, nullptr, D, 512);
  gemm_mfma<true, 1, false><<<dim3(2, Q / 128), blk, 0, stream>>>(
      query, Btq, (void*)Qf, nullptr, D, D);
  gemm_mfma<true, 1, false><<<dim3(2, Q / 128), blk, 0, stream>>>(
      geo, Btg, (void*)Gf, nullptr, 64, D);

  edge_attn<<<dim3(Q), blk, 0, stream>>>(s_idx, q_start, (const uint4*)KV,
                                         Qf, Gf, Opre, log_tau);

  gemm_mfma<false, 0, true><<<dim3(2, Q / 128), blk, 0, stream>>>(
      Opre, Bto, d_out, bo, D, D);
}